// Round 14
// baseline (144.389 us; speedup 1.0000x reference)
//
#include <hip/hip_runtime.h>
#include <hip/hip_bf16.h>

typedef short v8s __attribute__((ext_vector_type(8)));
typedef float v4f __attribute__((ext_vector_type(4)));

#define THREADS 384      // 6 waves
#define WAVES   6
#define BMROWS  192      // 32 rows per wave (2 M-tiles)
#define BTOTAL  262144
// wf frag indices (93 frags in d_ws)
#define W1F     0        // 49 frags
#define W2F     49       // 28 frags
#define W3F     77       // 16 frags
// LDS: [W2: 28 frags @0..28K) [W1: 49 frags @28K..77K)
// slabs (6 x 8KB = 48KB) overlay the W1 region after the post-layer1 barrier;
// W3 (16 frags) overwrites the W2 region after the post-layer2 barrier.
#define W1LDS   28
#define SLABB   28672
#define LDS_TOTAL 78848   // 77 KiB -> 2 blocks/CU -> 12 waves/CU (3/SIMD)

__device__ __forceinline__ unsigned short f2bf(float f) {
    union { __hip_bfloat16 h; unsigned short u; } c;
    c.h = __float2bfloat16(f);
    return c.u;
}
__device__ __forceinline__ unsigned pk2(float a, float b) {
    return (unsigned)f2bf(a) | ((unsigned)f2bf(b) << 16);
}
__device__ __forceinline__ v4f mfma16(v8s a, v8s b, v4f c) {
    return __builtin_amdgcn_mfma_f32_16x16x32_bf16(a, b, c, 0, 0, 0);
}
__device__ __forceinline__ v8s mkfrag(float4 a, float4 b) {
    union { unsigned u[4]; v8s s; } t;
    t.u[0] = pk2(a.x, a.y); t.u[1] = pk2(a.z, a.w);
    t.u[2] = pk2(b.x, b.y); t.u[3] = pk2(b.z, b.w);
    return t.s;
}
__device__ __forceinline__ void gload_lds16(const void* g, void* l) {
    __builtin_amdgcn_global_load_lds(
        (const __attribute__((address_space(1))) void*)g,
        (__attribute__((address_space(3))) void*)l, 16, 0, 0);
}

// ---- prep: weights -> MFMA B-fragment layout (bf16, zero-padded) ----------
// frag(nt,kc): lane l holds B[k = kc*32+(l>>4)*8+j][n = nt*16+(l&15)], j=0..7
__global__ void prep_weights(const float* __restrict__ W1,
                             const float* __restrict__ W2,
                             const float* __restrict__ W3,
                             uint4* __restrict__ wf) {
    const int bid = blockIdx.x, l = threadIdx.x;
    const float* W; int K, N, KC, base, f;
    if (bid < 49)      { W = W1; K = 200; N = 100; KC = 7; base = W1F * 64; f = bid; }
    else if (bid < 77) { W = W2; K = 100; N = 100; KC = 4; base = W2F * 64; f = bid - 49; }
    else               { W = W3; K = 100; N = 64;  KC = 4; base = W3F * 64; f = bid - 77; }
    const int kc = f % KC;
    const int n  = (f / KC) * 16 + (l & 15);
    unsigned u[4];
    #pragma unroll
    for (int p = 0; p < 4; ++p) {
        const int k0 = kc * 32 + (l >> 4) * 8 + p * 2;
        const float a = (k0     < K && n < N) ? W[(size_t)k0 * N + n]       : 0.f;
        const float b = (k0 + 1 < K && n < N) ? W[(size_t)(k0 + 1) * N + n] : 0.f;
        u[p] = pk2(a, b);
    }
    wf[base + f * 64 + l] = make_uint4(u[0], u[1], u[2], u[3]);
}

// Per-wave 8 KiB slab overlaying the W1 region: [32 rows][256 B], XOR-16 swz.
__device__ __forceinline__ int sladdr(int wid, int row, int byte) {
    return SLABB + (wid << 13) + (row << 8) +
           ((((byte >> 4) ^ row) & 15) << 4) + (byte & 15);
}

__global__ __launch_bounds__(THREADS, 3)   // 170-reg cap -> 3 waves/SIMD
void ar_gas_v14(const float* __restrict__ x,
                const float* __restrict__ last_mu,
                const float* __restrict__ last_sigma,
                const float* __restrict__ p_amu, const float* __restrict__ p_as,
                const float* __restrict__ p_bmu, const float* __restrict__ p_bs,
                const float* __restrict__ p_omu, const float* __restrict__ p_os,
                const float* __restrict__ p_nu,  const float* __restrict__ p_ns,
                const float* __restrict__ b1, const float* __restrict__ b2,
                const float* __restrict__ b3,
                const uint4* __restrict__ wf,
                float* __restrict__ out)
{
    extern __shared__ __align__(16) unsigned char L[];
    const int tid  = threadIdx.x;
    const int lane = tid & 63;
    const int wid  = tid >> 6;
    const int l15  = lane & 15;
    const int l4   = lane >> 4;
    const int blk  = blockIdx.x;

    // wave-private global rows [gw, gw+32); tail waves (gw >= B) compute
    // garbage on clamped loads and skip their stores.
    const size_t gw_raw = (size_t)blk * BMROWS + (size_t)wid * 32;
    const bool   active = (gw_raw < BTOTAL);
    const size_t gw     = active ? gw_raw : 0;

    const float* xp0 = x + (gw + l15) * 200;        // mt=0 A-rows
    const float* xp1 = x + (gw + 16 + l15) * 200;   // mt=1 A-rows

    // hoisted state loads: consumed ~5K cyc later at GAS (free latency cover)
    const float mu_init = last_mu[gw + (lane & 31)];
    const float s2_init = last_sigma[gw + (lane & 31)];

#define XLOAD(d0, d1, xp, kk)                                           \
    { int kb = (kk) * 32 + l4 * 8;                                      \
      kb = (kb + 8 <= 200) ? kb : 168;                                  \
      d0 = *(const float4*)((xp) + kb);                                 \
      d1 = *(const float4*)((xp) + kb + 4); }

    // X prologue loads (in flight during frag staging; barrier drains all)
    float4 c0a, c0b, c1a, c1b;
    XLOAD(c0a, c0b, xp0, 0);
    XLOAD(c1a, c1b, xp1, 0);

    // ---- stage W2 (LDS slots 0..27) + W1 (slots 28..76), 6 waves ----
    for (int s = wid; s < 77; s += WAVES) {
        const int src = (s < 28) ? (W2F + s) : (W1F + s - 28);
        gload_lds16(wf + src * 64 + lane, L + s * 1024);
    }
    __syncthreads();   // barrier 1: frags resident (vmcnt(0) drain)

#define FRAG(slot) (*(const uint4*)(&L[(slot) * 1024 + lane * 16]))

    // ================= layer 1: h1 = relu(X @ W1 + b1) =================
    v4f acc[2][7];                          // 56 accumulator regs
    #pragma unroll
    for (int mt = 0; mt < 2; ++mt)
        #pragma unroll
        for (int nt = 0; nt < 7; ++nt) acc[mt][nt] = (v4f){0.f, 0.f, 0.f, 0.f};

    #pragma unroll
    for (int kc = 0; kc < 7; ++kc) {
        uint4 bu[7];
        #pragma unroll
        for (int nt = 0; nt < 7; ++nt) bu[nt] = FRAG(W1LDS + nt * 7 + kc);
        const v8s af0 = mkfrag(c0a, c0b);
        const v8s af1 = mkfrag(c1a, c1b);
        if (kc < 6) {                       // prefetch next X chunk
            XLOAD(c0a, c0b, xp0, kc + 1);
            XLOAD(c1a, c1b, xp1, kc + 1);
        }
        #pragma unroll
        for (int nt = 0; nt < 7; ++nt) {
            const v8s bf = *(const v8s*)&bu[nt];
            acc[0][nt] = mfma16(af0, bf, acc[0][nt]);
            acc[1][nt] = mfma16(af1, bf, acc[1][nt]);
        }
    }
#undef XLOAD

    __syncthreads();   // barrier 2: all waves done reading W1 -> slabs overlay

    // epilogue -> slab (bf16 [32][128]); bias loaded here, not held through L1
    {
        float bv[7];
        #pragma unroll
        for (int nt = 0; nt < 7; ++nt) {
            const int c = nt * 16 + l15;
            bv[nt] = (c < 100) ? b1[c] : 0.f;
        }
        #pragma unroll
        for (int mt = 0; mt < 2; ++mt)
            #pragma unroll
            for (int nt = 0; nt < 7; ++nt) {
                #pragma unroll
                for (int r = 0; r < 4; ++r) {
                    const int row = mt * 16 + l4 * 4 + r;
                    const int c   = nt * 16 + l15;
                    const float v = fmaxf(acc[mt][nt][r] + bv[nt], 0.f);
                    *(unsigned short*)(&L[sladdr(wid, row, c * 2)]) = f2bf(v);
                }
            }
    }
    // zero cols 112..127 (100..111 zero via zero-padded W1 frags)
    *(uint4*)(&L[sladdr(wid, lane >> 1, 224 + (lane & 1) * 16)]) =
        make_uint4(0, 0, 0, 0);

    // ================= layer 2: h2 = relu(h1 @ W2 + b2) =================
    v4f acc2[2][7];
    #pragma unroll
    for (int mt = 0; mt < 2; ++mt)
        #pragma unroll
        for (int nt = 0; nt < 7; ++nt) acc2[mt][nt] = (v4f){0.f, 0.f, 0.f, 0.f};

    #pragma unroll
    for (int kc = 0; kc < 4; ++kc) {
        uint4 bu[7];
        #pragma unroll
        for (int nt = 0; nt < 7; ++nt) bu[nt] = FRAG(nt * 4 + kc);   // W2 slots
        uint4 t0 = *(const uint4*)(&L[sladdr(wid, l15,      kc * 64 + l4 * 16)]);
        uint4 t1 = *(const uint4*)(&L[sladdr(wid, 16 + l15, kc * 64 + l4 * 16)]);
        const v8s af0 = *(v8s*)&t0;
        const v8s af1 = *(v8s*)&t1;
        #pragma unroll
        for (int nt = 0; nt < 7; ++nt) {
            const v8s bf = *(const v8s*)&bu[nt];
            acc2[0][nt] = mfma16(af0, bf, acc2[0][nt]);
            acc2[1][nt] = mfma16(af1, bf, acc2[1][nt]);
        }
    }

    __syncthreads();   // barrier 3: all waves done reading W2 region

    // stage W3 into the dead W2 region (slots 0..15); latency hidden by epilogue
    for (int s = wid; s < 16; s += WAVES)
        gload_lds16(wf + (W3F + s) * 64 + lane, L + s * 1024);

    // h2 -> slab (overlaps W3 staging); pad cols keep zeros
    {
        float bv[7];
        #pragma unroll
        for (int nt = 0; nt < 7; ++nt) {
            const int c = nt * 16 + l15;
            bv[nt] = (c < 100) ? b2[c] : 0.f;
        }
        #pragma unroll
        for (int mt = 0; mt < 2; ++mt)
            #pragma unroll
            for (int nt = 0; nt < 7; ++nt) {
                #pragma unroll
                for (int r = 0; r < 4; ++r) {
                    const int row = mt * 16 + l4 * 4 + r;
                    const int c   = nt * 16 + l15;
                    const float v = fmaxf(acc2[mt][nt][r] + bv[nt], 0.f);
                    *(unsigned short*)(&L[sladdr(wid, row, c * 2)]) = f2bf(v);
                }
            }
    }

    __syncthreads();   // barrier 4: W3 resident (vmcnt drain) + h2 visible

    // ================= layer 3: DP = h2 @ W3 + b3 =================
    v4f acc3[2][4];
    #pragma unroll
    for (int mt = 0; mt < 2; ++mt)
        #pragma unroll
        for (int nt = 0; nt < 4; ++nt) acc3[mt][nt] = (v4f){0.f, 0.f, 0.f, 0.f};

    #pragma unroll
    for (int kc = 0; kc < 4; ++kc) {
        uint4 bu[4];
        #pragma unroll
        for (int nt = 0; nt < 4; ++nt) bu[nt] = FRAG(nt * 4 + kc);   // W3 slots
        uint4 t0 = *(const uint4*)(&L[sladdr(wid, l15,      kc * 64 + l4 * 16)]);
        uint4 t1 = *(const uint4*)(&L[sladdr(wid, 16 + l15, kc * 64 + l4 * 16)]);
        const v8s af0 = *(v8s*)&t0;
        const v8s af1 = *(v8s*)&t1;
        #pragma unroll
        for (int nt = 0; nt < 4; ++nt) {
            const v8s bf = *(const v8s*)&bu[nt];
            acc3[0][nt] = mfma16(af0, bf, acc3[0][nt]);
            acc3[1][nt] = mfma16(af1, bf, acc3[1][nt]);
        }
    }
#undef FRAG

    // DP (f32 [32][64]) overwrites slab (h2 reads precede in program order)
    {
        float bv[4];
        #pragma unroll
        for (int nt = 0; nt < 4; ++nt) bv[nt] = b3[nt * 16 + l15];
        #pragma unroll
        for (int mt = 0; mt < 2; ++mt)
            #pragma unroll
            for (int nt = 0; nt < 4; ++nt) {
                #pragma unroll
                for (int r = 0; r < 4; ++r) {
                    const int row = mt * 16 + l4 * 4 + r;
                    const int c   = nt * 16 + l15;
                    *(float*)(&L[sladdr(wid, row, c * 4)]) = acc3[mt][nt][r] + bv[nt];
                }
            }
    }

    // ====== Student-t GAS recurrence: per-wave, lane<32 owns one row ======
    if (lane < 32) {
        float mu = mu_init;
        float s2 = s2_init;
        const float anu = *p_nu,  ans = *p_ns;
        const float aMu = *p_amu, aSg = *p_as;
        const float bMu = *p_bmu, bSg = *p_bs;
        const float oMu = *p_omu, oSg = *p_os;
        const float w   = 1.f + __builtin_amdgcn_rcpf(anu);
        const float cmu = ans * aMu * w;
        const float cs  = ans * aSg * w;
        const float bs2 = bSg - ans * aSg;

#define GAS_STEP(Y, O)                                                  \
        {   const float e    = (Y) - mu;                                \
            const float nus2 = anu * s2;                                \
            const float den  = fmaf(e, e, nus2);                        \
            const float r0   = __builtin_amdgcn_rcpf(den);              \
            const float p    = e * nus2 * r0;                           \
            mu = fmaf(cmu, p, fmaf(bMu, mu, oMu));                      \
            s2 = fmaf(cs, e * p, fmaf(bs2, s2, oSg));                   \
            (O) = fmaf((Y), __builtin_amdgcn_sqrtf(s2), mu); }

        #pragma unroll
        for (int q = 0; q < 16; ++q) {
            float4 d = *(float4*)(&L[sladdr(wid, lane, q * 16)]);
            float o0, o1, o2, o3;
            GAS_STEP(d.x, o0); GAS_STEP(d.y, o1);
            GAS_STEP(d.z, o2); GAS_STEP(d.w, o3);
            *(float4*)(&L[sladdr(wid, lane, q * 16)]) = make_float4(o0, o1, o2, o3);
        }
#undef GAS_STEP
    }

    // ============ wave-wide coalesced float4 store (no barrier) ============
    if (active) {
        #pragma unroll
        for (int i = 0; i < 8; ++i) {
            const int fi  = i * 64 + lane;       // 512 float4 = 32 rows x 16
            const int row = fi >> 4, q = fi & 15;
            float4 v = *(float4*)(&L[sladdr(wid, row, q * 16)]);
            ((float4*)out)[gw * 16 + fi] = v;
        }
    }
}

extern "C" void kernel_launch(void* const* d_in, const int* in_sizes, int n_in,
                              void* d_out, int out_size, void* d_ws, size_t ws_size,
                              hipStream_t stream) {
    const float* x          = (const float*)d_in[0];
    const float* last_mu    = (const float*)d_in[1];
    const float* last_sigma = (const float*)d_in[2];
    const float* amu        = (const float*)d_in[3];
    const float* asig       = (const float*)d_in[4];
    const float* bmu        = (const float*)d_in[5];
    const float* bsig       = (const float*)d_in[6];
    const float* omu        = (const float*)d_in[7];
    const float* osig       = (const float*)d_in[8];
    const float* nu         = (const float*)d_in[9];
    const float* ns         = (const float*)d_in[10];
    const float* W1         = (const float*)d_in[11];
    const float* b1         = (const float*)d_in[12];
    const float* W2         = (const float*)d_in[13];
    const float* b2         = (const float*)d_in[14];
    const float* W3         = (const float*)d_in[15];
    const float* b3         = (const float*)d_in[16];
    float* out = (float*)d_out;

    uint4* wf = (uint4*)d_ws;   // 95,232 B fragment table (93 frags)
    prep_weights<<<93, 64, 0, stream>>>(W1, W2, W3, wf);

    hipFuncSetAttribute((const void*)ar_gas_v14,
                        hipFuncAttributeMaxDynamicSharedMemorySize, LDS_TOTAL);

    const int B = in_sizes[1];                 // 262144
    dim3 grid((B + BMROWS - 1) / BMROWS), block(THREADS);   // 1366 blocks
    ar_gas_v14<<<grid, block, LDS_TOTAL, stream>>>(
        x, last_mu, last_sigma,
        amu, asig, bmu, bsig, omu, osig, nu, ns,
        b1, b2, b3, wf, out);
}

// Round 15
// 140.681 us; speedup vs baseline: 1.0264x; 1.0264x over previous
//
#include <hip/hip_runtime.h>
#include <hip/hip_bf16.h>

typedef short v8s __attribute__((ext_vector_type(8)));
typedef float v4f __attribute__((ext_vector_type(4)));

#define THREADS 1024     // 16 waves, persistent: 1 block per CU
#define NBLOCKS 256
#define NTILES  4        // 4 tiles x 256 rows = 1024 rows per block
// frag slots (93, resident in LDS the whole kernel)
#define W1F     0        // 49
#define W2F     49       // 28
#define W3F     77       // 16
#define SLABB   95232                      // 93 KiB frag region
#define LDS_TOTAL (95232 + 16 * 4096)      // 160,768 B <= 160 KiB pool

__device__ __forceinline__ unsigned short f2bf(float f) {
    union { __hip_bfloat16 h; unsigned short u; } c;
    c.h = __float2bfloat16(f);
    return c.u;
}
__device__ __forceinline__ unsigned pk2(float a, float b) {
    return (unsigned)f2bf(a) | ((unsigned)f2bf(b) << 16);
}
__device__ __forceinline__ v4f mfma16(v8s a, v8s b, v4f c) {
    return __builtin_amdgcn_mfma_f32_16x16x32_bf16(a, b, c, 0, 0, 0);
}
__device__ __forceinline__ v8s mkfrag(float4 a, float4 b) {
    union { unsigned u[4]; v8s s; } t;
    t.u[0] = pk2(a.x, a.y); t.u[1] = pk2(a.z, a.w);
    t.u[2] = pk2(b.x, b.y); t.u[3] = pk2(b.z, b.w);
    return t.s;
}
__device__ __forceinline__ void gload_lds16(const void* g, void* l) {
    __builtin_amdgcn_global_load_lds(
        (const __attribute__((address_space(1))) void*)g,
        (__attribute__((address_space(3))) void*)l, 16, 0, 0);
}

// ---- prep: weights -> MFMA B-fragment layout (bf16, zero-padded) ----------
// frag(nt,kc): lane l holds B[k = kc*32+(l>>4)*8+j][n = nt*16+(l&15)], j=0..7
__global__ void prep_weights(const float* __restrict__ W1,
                             const float* __restrict__ W2,
                             const float* __restrict__ W3,
                             uint4* __restrict__ wf) {
    const int bid = blockIdx.x, l = threadIdx.x;
    const float* W; int K, N, KC, base, f;
    if (bid < 49)      { W = W1; K = 200; N = 100; KC = 7; base = W1F * 64; f = bid; }
    else if (bid < 77) { W = W2; K = 100; N = 100; KC = 4; base = W2F * 64; f = bid - 49; }
    else               { W = W3; K = 100; N = 64;  KC = 4; base = W3F * 64; f = bid - 77; }
    const int kc = f % KC;
    const int n  = (f / KC) * 16 + (l & 15);
    unsigned u[4];
    #pragma unroll
    for (int p = 0; p < 4; ++p) {
        const int k0 = kc * 32 + (l >> 4) * 8 + p * 2;
        const float a = (k0     < K && n < N) ? W[(size_t)k0 * N + n]       : 0.f;
        const float b = (k0 + 1 < K && n < N) ? W[(size_t)(k0 + 1) * N + n] : 0.f;
        u[p] = pk2(a, b);
    }
    wf[base + f * 64 + l] = make_uint4(u[0], u[1], u[2], u[3]);
}

// Per-wave 4 KiB slab: [16 rows][256 B], XOR-16 granule swizzle.
// Reused h1(bf16[16][128]) -> h2 -> DP(f32[16][64]) via in-wave DS ordering.
__device__ __forceinline__ int sladdr(int wid, int row, int byte) {
    return SLABB + (wid << 12) + (row << 8) +
           ((((byte >> 4) ^ row) & 15) << 4) + (byte & 15);
}

__global__ __launch_bounds__(THREADS, 4)   // 128-reg cap -> 4 waves/SIMD
void ar_gas_v15(const float* __restrict__ x,
                const float* __restrict__ last_mu,
                const float* __restrict__ last_sigma,
                const float* __restrict__ p_amu, const float* __restrict__ p_as,
                const float* __restrict__ p_bmu, const float* __restrict__ p_bs,
                const float* __restrict__ p_omu, const float* __restrict__ p_os,
                const float* __restrict__ p_nu,  const float* __restrict__ p_ns,
                const float* __restrict__ b1, const float* __restrict__ b2,
                const float* __restrict__ b3,
                const uint4* __restrict__ wf,
                float* __restrict__ out)
{
    extern __shared__ __align__(16) unsigned char L[];
    const int tid  = threadIdx.x;
    const int lane = tid & 63;
    const int wid  = tid >> 6;
    const int l15  = lane & 15;
    const int l4   = lane >> 4;
    const int blk  = blockIdx.x;

    // GAS scalars (uniform -> scalar loads, held in SGPRs)
    const float anu = *p_nu,  ans = *p_ns;
    const float aMu = *p_amu, aSg = *p_as;
    const float bMu = *p_bmu, bSg = *p_bs;
    const float oMu = *p_omu, oSg = *p_os;
    const float wS  = 1.f + __builtin_amdgcn_rcpf(anu);
    const float cmu = ans * aMu * wS;
    const float cs  = ans * aSg * wS;
    const float bs2 = bSg - ans * aSg;

#define XLOAD(d0, d1, xp, kk)                                           \
    { int kb = (kk) * 32 + l4 * 8;                                      \
      kb = (kb + 8 <= 200) ? kb : 168;                                  \
      d0 = *(const float4*)((xp) + kb);                                 \
      d1 = *(const float4*)((xp) + kb + 4); }

    // tile 0 row base; rolling X window 3 chunks deep (24 VGPR)
    size_t gw = (size_t)blk * (NTILES * 256) + (size_t)wid * 16;
    float4 xv[3][2];
    {
        const float* xp = x + (gw + l15) * 200;
        XLOAD(xv[0][0], xv[0][1], xp, 0);
        XLOAD(xv[1][0], xv[1][1], xp, 1);
        XLOAD(xv[2][0], xv[2][1], xp, 2);
    }

    // ---- one-time stage: all 93 frags -> LDS (never overwritten) ----
    for (int s = wid; s < 93; s += 16)
        gload_lds16(wf + s * 64 + lane, L + s * 1024);
    __syncthreads();   // THE only barrier in the kernel

#define FRAG(slot) (*(const uint4*)(&L[(slot) * 1024 + lane * 16]))

    #pragma unroll 1
    for (int t = 0; t < NTILES; ++t) {
        const float* xp = x + (gw + l15) * 200;

        // hoisted state loads: consumed ~3K cyc later at GAS
        const float mu_init = last_mu[gw + l15];
        const float s2_init = last_sigma[gw + l15];

        // ================= layer 1: h1 = relu(X @ W1 + b1) ==============
        v4f acc[7];
        #pragma unroll
        for (int nt = 0; nt < 7; ++nt) acc[nt] = (v4f){0.f, 0.f, 0.f, 0.f};

        #pragma unroll
        for (int kc = 0; kc < 7; ++kc) {
            uint4 bu[7];
            #pragma unroll
            for (int nt = 0; nt < 7; ++nt) bu[nt] = FRAG(W1F + nt * 7 + kc);
            const v8s af = mkfrag(xv[kc % 3][0], xv[kc % 3][1]);
            if (kc < 4) XLOAD(xv[kc % 3][0], xv[kc % 3][1], xp, kc + 3);
            #pragma unroll
            for (int nt = 0; nt < 7; ++nt)
                acc[nt] = mfma16(af, *(const v8s*)&bu[nt], acc[nt]);
        }

        // epilogue -> slab (bf16 [16][128]); transient bias
        {
            float bv[7];
            #pragma unroll
            for (int nt = 0; nt < 7; ++nt) {
                const int c = nt * 16 + l15;
                bv[nt] = (c < 100) ? b1[c] : 0.f;
            }
            #pragma unroll
            for (int nt = 0; nt < 7; ++nt) {
                #pragma unroll
                for (int r = 0; r < 4; ++r) {
                    const int row = l4 * 4 + r;
                    const int c   = nt * 16 + l15;
                    const float v = fmaxf(acc[nt][r] + bv[nt], 0.f);
                    *(unsigned short*)(&L[sladdr(wid, row, c * 2)]) = f2bf(v);
                }
            }
        }
        // zero cols 112..127 (100..111 zero via zero-padded W1 frags)
        if (lane < 32)
            *(uint4*)(&L[sladdr(wid, lane >> 1, 224 + (lane & 1) * 16)]) =
                make_uint4(0, 0, 0, 0);

        // ================= layer 2: h2 = relu(h1 @ W2 + b2) =============
        v4f acc2[7];
        #pragma unroll
        for (int nt = 0; nt < 7; ++nt) acc2[nt] = (v4f){0.f, 0.f, 0.f, 0.f};
        #pragma unroll
        for (int kc = 0; kc < 4; ++kc) {
            uint4 bu[7];
            #pragma unroll
            for (int nt = 0; nt < 7; ++nt) bu[nt] = FRAG(W2F + nt * 4 + kc);
            uint4 t0 = *(const uint4*)(&L[sladdr(wid, l15, kc * 64 + l4 * 16)]);
            const v8s af = *(v8s*)&t0;
            #pragma unroll
            for (int nt = 0; nt < 7; ++nt)
                acc2[nt] = mfma16(af, *(const v8s*)&bu[nt], acc2[nt]);
        }
        // h2 overwrites h1 in-place (in-wave DS ordering); pad cols keep zeros
        {
            float bv[7];
            #pragma unroll
            for (int nt = 0; nt < 7; ++nt) {
                const int c = nt * 16 + l15;
                bv[nt] = (c < 100) ? b2[c] : 0.f;
            }
            #pragma unroll
            for (int nt = 0; nt < 7; ++nt) {
                #pragma unroll
                for (int r = 0; r < 4; ++r) {
                    const int row = l4 * 4 + r;
                    const int c   = nt * 16 + l15;
                    const float v = fmaxf(acc2[nt][r] + bv[nt], 0.f);
                    *(unsigned short*)(&L[sladdr(wid, row, c * 2)]) = f2bf(v);
                }
            }
        }

        // ================= layer 3: DP = h2 @ W3 + b3 ===================
        v4f acc3[4];
        #pragma unroll
        for (int nt = 0; nt < 4; ++nt) acc3[nt] = (v4f){0.f, 0.f, 0.f, 0.f};
        #pragma unroll
        for (int kc = 0; kc < 4; ++kc) {
            uint4 bu[4];
            #pragma unroll
            for (int nt = 0; nt < 4; ++nt) bu[nt] = FRAG(W3F + nt * 4 + kc);
            uint4 t0 = *(const uint4*)(&L[sladdr(wid, l15, kc * 64 + l4 * 16)]);
            const v8s af = *(v8s*)&t0;
            #pragma unroll
            for (int nt = 0; nt < 4; ++nt)
                acc3[nt] = mfma16(af, *(const v8s*)&bu[nt], acc3[nt]);
        }
        // DP (f32 [16][64]) overwrites slab (h2 reads precede in program order)
        {
            float bv[4];
            #pragma unroll
            for (int nt = 0; nt < 4; ++nt) bv[nt] = b3[nt * 16 + l15];
            #pragma unroll
            for (int nt = 0; nt < 4; ++nt) {
                #pragma unroll
                for (int r = 0; r < 4; ++r) {
                    const int row = l4 * 4 + r;
                    const int c   = nt * 16 + l15;
                    *(float*)(&L[sladdr(wid, row, c * 4)]) = acc3[nt][r] + bv[nt];
                }
            }
        }

        // cross-tile X prefetch: next tile's chunks 0..2 issued NOW;
        // HBM latency hides under GAS + store (~2.5K cyc)
        const size_t gw_next = gw + 256;
        if (t < NTILES - 1) {
            const float* np = x + (gw_next + l15) * 200;
            XLOAD(xv[0][0], xv[0][1], np, 0);
            XLOAD(xv[1][0], xv[1][1], np, 1);
            XLOAD(xv[2][0], xv[2][1], np, 2);
        }

        // ====== Student-t GAS recurrence: per-wave, lane<16 owns one row ==
        if (lane < 16) {
            float mu = mu_init;
            float s2 = s2_init;
#define GAS_STEP(Y, O)                                                  \
            {   const float e    = (Y) - mu;                            \
                const float nus2 = anu * s2;                            \
                const float den  = fmaf(e, e, nus2);                    \
                const float r0   = __builtin_amdgcn_rcpf(den);          \
                const float p    = e * nus2 * r0;                       \
                mu = fmaf(cmu, p, fmaf(bMu, mu, oMu));                  \
                s2 = fmaf(cs, e * p, fmaf(bs2, s2, oSg));               \
                (O) = fmaf((Y), __builtin_amdgcn_sqrtf(s2), mu); }
            #pragma unroll
            for (int q = 0; q < 16; ++q) {
                float4 d = *(float4*)(&L[sladdr(wid, lane, q * 16)]);
                float o0, o1, o2, o3;
                GAS_STEP(d.x, o0); GAS_STEP(d.y, o1);
                GAS_STEP(d.z, o2); GAS_STEP(d.w, o3);
                *(float4*)(&L[sladdr(wid, lane, q * 16)]) =
                    make_float4(o0, o1, o2, o3);
            }
#undef GAS_STEP
        }

        // ============ wave-wide coalesced float4 store (no barrier) =======
        #pragma unroll
        for (int i = 0; i < 4; ++i) {
            const int fi  = i * 64 + lane;       // 256 float4 = 16 rows x 16
            const int row = fi >> 4, q = fi & 15;
            float4 v = *(float4*)(&L[sladdr(wid, row, q * 16)]);
            ((float4*)out)[gw * 16 + fi] = v;
        }

        gw = gw_next;
    }
#undef FRAG
#undef XLOAD
}

extern "C" void kernel_launch(void* const* d_in, const int* in_sizes, int n_in,
                              void* d_out, int out_size, void* d_ws, size_t ws_size,
                              hipStream_t stream) {
    const float* x          = (const float*)d_in[0];
    const float* last_mu    = (const float*)d_in[1];
    const float* last_sigma = (const float*)d_in[2];
    const float* amu        = (const float*)d_in[3];
    const float* asig       = (const float*)d_in[4];
    const float* bmu        = (const float*)d_in[5];
    const float* bsig       = (const float*)d_in[6];
    const float* omu        = (const float*)d_in[7];
    const float* osig       = (const float*)d_in[8];
    const float* nu         = (const float*)d_in[9];
    const float* ns         = (const float*)d_in[10];
    const float* W1         = (const float*)d_in[11];
    const float* b1         = (const float*)d_in[12];
    const float* W2         = (const float*)d_in[13];
    const float* b2         = (const float*)d_in[14];
    const float* W3         = (const float*)d_in[15];
    const float* b3         = (const float*)d_in[16];
    float* out = (float*)d_out;

    uint4* wf = (uint4*)d_ws;   // 95,232 B fragment table (93 frags)
    prep_weights<<<93, 64, 0, stream>>>(W1, W2, W3, wf);

    hipFuncSetAttribute((const void*)ar_gas_v15,
                        hipFuncAttributeMaxDynamicSharedMemorySize, LDS_TOTAL);

    dim3 grid(NBLOCKS), block(THREADS);        // persistent: 1 block/CU
    ar_gas_v15<<<grid, block, LDS_TOTAL, stream>>>(
        x, last_mu, last_sigma,
        amu, asig, bmu, bsig, omu, osig, nu, ns,
        b1, b2, b3, wf, out);
}

// Round 17
// 83.323 us; speedup vs baseline: 1.7329x; 1.6884x over previous
//
#include <hip/hip_runtime.h>
#include <hip/hip_bf16.h>

typedef short v8s __attribute__((ext_vector_type(8)));
typedef float v4f __attribute__((ext_vector_type(4)));

#define THREADS 512      // 8 waves x 16 rows = 128 rows/block
#define WAVES   8
#define BMROWS  128
// d_ws frag order: W1 0-48, W2 49-76, W3 77-92
#define W1F     0
#define W2F     49
#define W3F     77
// LDS map: W1 [0,50176) live until barrier2. After barrier2:
//   slabs overlay [0,33792) (W1 slots 0..32), and W3 is staged into
//   [33792,50176) (dead W1 slots 33..48), fenced by barrier3.
// W2 [50176,78848) resident the whole kernel.
#define W3B     33792
#define W2B     50176
#define SLAB_STRIDE 264          // 66 dwords: bank += 2 per row -> low conflict
#define SLAB_SIZE   4224         // 16 rows * 264
#define LDS_TOTAL   78848        // 77 KiB -> 2 blocks/CU

__device__ __forceinline__ unsigned short f2bf(float f) {
    union { __hip_bfloat16 h; unsigned short u; } c;
    c.h = __float2bfloat16(f);
    return c.u;
}
__device__ __forceinline__ unsigned pk2(float a, float b) {
    return (unsigned)f2bf(a) | ((unsigned)f2bf(b) << 16);
}
__device__ __forceinline__ v4f mfma16(v8s a, v8s b, v4f c) {
    return __builtin_amdgcn_mfma_f32_16x16x32_bf16(a, b, c, 0, 0, 0);
}
__device__ __forceinline__ v8s mkfrag(float4 a, float4 b) {
    union { unsigned u[4]; v8s s; } t;
    t.u[0] = pk2(a.x, a.y); t.u[1] = pk2(a.z, a.w);
    t.u[2] = pk2(b.x, b.y); t.u[3] = pk2(b.z, b.w);
    return t.s;
}
__device__ __forceinline__ void gload_lds16(const void* g, void* l) {
    __builtin_amdgcn_global_load_lds(
        (const __attribute__((address_space(1))) void*)g,
        (__attribute__((address_space(3))) void*)l, 16, 0, 0);
}

// ---- prep: weights -> MFMA B-fragment layout (bf16, zero-padded) ----------
// frag(nt,kc): lane l holds B[k = kc*32+(l>>4)*8+j][n = nt*16+(l&15)], j=0..7
__global__ void prep_weights(const float* __restrict__ W1,
                             const float* __restrict__ W2,
                             const float* __restrict__ W3,
                             uint4* __restrict__ wf) {
    const int bid = blockIdx.x, l = threadIdx.x;
    const float* W; int K, N, KC, base, f;
    if (bid < 49)      { W = W1; K = 200; N = 100; KC = 7; base = W1F * 64; f = bid; }
    else if (bid < 77) { W = W2; K = 100; N = 100; KC = 4; base = W2F * 64; f = bid - 49; }
    else               { W = W3; K = 100; N = 64;  KC = 4; base = W3F * 64; f = bid - 77; }
    const int kc = f % KC;
    const int n  = (f / KC) * 16 + (l & 15);
    unsigned u[4];
    #pragma unroll
    for (int p = 0; p < 4; ++p) {
        const int k0 = kc * 32 + (l >> 4) * 8 + p * 2;
        const float a = (k0     < K && n < N) ? W[(size_t)k0 * N + n]       : 0.f;
        const float b = (k0 + 1 < K && n < N) ? W[(size_t)(k0 + 1) * N + n] : 0.f;
        u[p] = pk2(a, b);
    }
    wf[base + f * 64 + l] = make_uint4(u[0], u[1], u[2], u[3]);
}

__global__ __launch_bounds__(THREADS, 2)   // cap 256: the only no-spill regime
void ar_gas_v17(const float* __restrict__ x,
                const float* __restrict__ last_mu,
                const float* __restrict__ last_sigma,
                const float* __restrict__ p_amu, const float* __restrict__ p_as,
                const float* __restrict__ p_bmu, const float* __restrict__ p_bs,
                const float* __restrict__ p_omu, const float* __restrict__ p_os,
                const float* __restrict__ p_nu,  const float* __restrict__ p_ns,
                const float* __restrict__ b1, const float* __restrict__ b2,
                const float* __restrict__ b3,
                const uint4* __restrict__ wf,
                float* __restrict__ out)
{
    extern __shared__ __align__(16) unsigned char L[];
    const int tid  = threadIdx.x;
    const int lane = tid & 63;
    const int wid  = tid >> 6;
    const int l15  = lane & 15;
    const int l4   = lane >> 4;
    const int blk  = blockIdx.x;

    // wave-private global rows [gw, gw+16)
    const size_t gw = (size_t)blk * BMROWS + (size_t)wid * 16;
    const float* xp = x + (gw + l15) * 200;

    // ---- ALL per-row VMEM up front: X row (56 VGPR) + GAS state ----
    float4 xv[7][2];
    #pragma unroll
    for (int kc = 0; kc < 7; ++kc) {
        int kb = kc * 32 + l4 * 8;
        kb = (kb + 8 <= 200) ? kb : 168;     // clamp: garbage x zero-pad W1 = 0
        xv[kc][0] = *(const float4*)(xp + kb);
        xv[kc][1] = *(const float4*)(xp + kb + 4);
    }
    const float mu_init = last_mu[gw + l15];
    const float s2_init = last_sigma[gw + l15];

    // stage W1 (slots 0..48 -> [0,50176)) and W2 (-> W2B) ONLY. W3 comes later.
    for (int s = wid; s < 77; s += WAVES) {
        unsigned char* dst = (s < 49) ? (L + s * 1024)
                                      : (L + W2B + (s - 49) * 1024);
        gload_lds16(wf + s * 64 + lane, dst);
    }
    __syncthreads();   // barrier 1: vmcnt(0) drain -> X in regs, W1/W2 in LDS

#define FRAG_W1(f)  (*(const uint4*)(&L[(f) * 1024 + lane * 16]))
#define FRAG_W2(f)  (*(const uint4*)(&L[W2B + (f) * 1024 + lane * 16]))
#define FRAG_W3(f)  (*(const uint4*)(&L[W3B + (f) * 1024 + lane * 16]))

    // affine slab bases (all ds offsets below are compile-time constants)
    const int sb      = wid * SLAB_SIZE;
    const int sb_epi  = sb + (l4 * 4) * SLAB_STRIDE + l15 * 2;  // + r*264 + nt*32
    const int sb_rd   = sb + l15 * SLAB_STRIDE + l4 * 16;       // + kc*64
    const int sb_dpw  = sb + (l4 * 4) * SLAB_STRIDE + l15 * 4;  // + r*264 + nt*64
    const int sb_gas  = sb + l15 * SLAB_STRIDE;                 // + q*16
    const int sb_st   = sb + l4 * SLAB_STRIDE + l15 * 16;       // + i*1056

    // ================= layer 1: h1 = relu(X @ W1 + b1) =================
    v4f acc[7];
    #pragma unroll
    for (int nt = 0; nt < 7; ++nt) acc[nt] = (v4f){0.f, 0.f, 0.f, 0.f};

    #pragma unroll
    for (int kc = 0; kc < 7; ++kc) {
        uint4 bu[7];
        #pragma unroll
        for (int nt = 0; nt < 7; ++nt) bu[nt] = FRAG_W1(nt * 7 + kc);
        const v8s af = mkfrag(xv[kc][0], xv[kc][1]);   // regs only, no waits
        #pragma unroll
        for (int nt = 0; nt < 7; ++nt)
            acc[nt] = mfma16(af, *(const v8s*)&bu[nt], acc[nt]);
    }

    __syncthreads();   // barrier 2: all waves done reading W1 -> region reusable

    // stage W3 into dead W1 slots 33..48 ([33792,50176)); latency hides
    // under the epilogue + layer 2 below; fenced by barrier 3.
    for (int s = wid; s < 16; s += WAVES)
        gload_lds16(wf + (W3F + s) * 64 + lane, L + W3B + s * 1024);

    // epilogue -> slab (bf16 [16 rows][stride 264]); transient bias
    {
        float bv[7];
        #pragma unroll
        for (int nt = 0; nt < 7; ++nt) {
            const int c = nt * 16 + l15;
            bv[nt] = (c < 100) ? b1[c] : 0.f;
        }
        #pragma unroll
        for (int nt = 0; nt < 7; ++nt)
            #pragma unroll
            for (int r = 0; r < 4; ++r) {
                const float v = fmaxf(acc[nt][r] + bv[nt], 0.f);
                *(unsigned short*)(&L[sb_epi + r * SLAB_STRIDE + nt * 32]) = f2bf(v);
            }
    }
    // zero cols 112..127 (bytes 224..255; 100..111 zero via zero-padded frags)
    if (lane < 32)
        *(uint4*)(&L[sb + (lane >> 1) * SLAB_STRIDE + 224 + (lane & 1) * 16]) =
            make_uint4(0, 0, 0, 0);

    // ================= layer 2: h2 = relu(h1 @ W2 + b2) =================
    v4f acc2[7];
    #pragma unroll
    for (int nt = 0; nt < 7; ++nt) acc2[nt] = (v4f){0.f, 0.f, 0.f, 0.f};
    #pragma unroll
    for (int kc = 0; kc < 4; ++kc) {
        uint4 bu[7];
        #pragma unroll
        for (int nt = 0; nt < 7; ++nt) bu[nt] = FRAG_W2(nt * 4 + kc);
        uint4 t0 = *(const uint4*)(&L[sb_rd + kc * 64]);
        const v8s af = *(v8s*)&t0;
        #pragma unroll
        for (int nt = 0; nt < 7; ++nt)
            acc2[nt] = mfma16(af, *(const v8s*)&bu[nt], acc2[nt]);
    }
    // h2 overwrites h1 in-place (in-wave DS ordering); pad cols keep zeros
    {
        float bv[7];
        #pragma unroll
        for (int nt = 0; nt < 7; ++nt) {
            const int c = nt * 16 + l15;
            bv[nt] = (c < 100) ? b2[c] : 0.f;
        }
        #pragma unroll
        for (int nt = 0; nt < 7; ++nt)
            #pragma unroll
            for (int r = 0; r < 4; ++r) {
                const float v = fmaxf(acc2[nt][r] + bv[nt], 0.f);
                *(unsigned short*)(&L[sb_epi + r * SLAB_STRIDE + nt * 32]) = f2bf(v);
            }
    }

    __syncthreads();   // barrier 3: vmcnt drain -> W3 resident and visible

    // ================= layer 3: DP = h2 @ W3 + b3 =================
    v4f acc3[4];
    #pragma unroll
    for (int nt = 0; nt < 4; ++nt) acc3[nt] = (v4f){0.f, 0.f, 0.f, 0.f};
    #pragma unroll
    for (int kc = 0; kc < 4; ++kc) {
        uint4 bu[4];
        #pragma unroll
        for (int nt = 0; nt < 4; ++nt) bu[nt] = FRAG_W3(nt * 4 + kc);
        uint4 t0 = *(const uint4*)(&L[sb_rd + kc * 64]);
        const v8s af = *(v8s*)&t0;
        #pragma unroll
        for (int nt = 0; nt < 4; ++nt)
            acc3[nt] = mfma16(af, *(const v8s*)&bu[nt], acc3[nt]);
    }
    // DP (f32 [16][64]) overwrites slab (all h2 reads precede in program order)
    {
        float bv[4];
        #pragma unroll
        for (int nt = 0; nt < 4; ++nt) bv[nt] = b3[nt * 16 + l15];
        #pragma unroll
        for (int nt = 0; nt < 4; ++nt)
            #pragma unroll
            for (int r = 0; r < 4; ++r)
                *(float*)(&L[sb_dpw + r * SLAB_STRIDE + nt * 64]) =
                    acc3[nt][r] + bv[nt];
    }

    // ====== Student-t GAS recurrence: lane<16 owns one row ======
    if (lane < 16) {
        float mu = mu_init;
        float s2 = s2_init;
        const float anu = *p_nu,  ans = *p_ns;
        const float aMu = *p_amu, aSg = *p_as;
        const float bMu = *p_bmu, bSg = *p_bs;
        const float oMu = *p_omu, oSg = *p_os;
        const float w   = 1.f + __builtin_amdgcn_rcpf(anu);
        const float cmu = ans * aMu * w;
        const float cs  = ans * aSg * w;
        const float bs2 = bSg - ans * aSg;

#define GAS_STEP(Y, O)                                                  \
        {   const float e    = (Y) - mu;                                \
            const float nus2 = anu * s2;                                \
            const float den  = fmaf(e, e, nus2);                        \
            const float r0   = __builtin_amdgcn_rcpf(den);              \
            const float p    = e * nus2 * r0;                           \
            mu = fmaf(cmu, p, fmaf(bMu, mu, oMu));                      \
            s2 = fmaf(cs, e * p, fmaf(bs2, s2, oSg));                   \
            (O) = fmaf((Y), __builtin_amdgcn_sqrtf(s2), mu); }

        #pragma unroll
        for (int q = 0; q < 16; ++q) {
            float4 d = *(float4*)(&L[sb_gas + q * 16]);
            float o0, o1, o2, o3;
            GAS_STEP(d.x, o0); GAS_STEP(d.y, o1);
            GAS_STEP(d.z, o2); GAS_STEP(d.w, o3);
            *(float4*)(&L[sb_gas + q * 16]) = make_float4(o0, o1, o2, o3);
        }
#undef GAS_STEP
    }

    // ============ wave-wide coalesced float4 store (no barrier) ============
    #pragma unroll
    for (int i = 0; i < 4; ++i) {
        // fi = i*64 + lane; row = i*4 + l4, q = l15
        float4 v = *(float4*)(&L[sb_st + i * (4 * SLAB_STRIDE)]);
        ((float4*)out)[gw * 16 + i * 64 + lane] = v;
    }
#undef FRAG_W1
#undef FRAG_W2
#undef FRAG_W3
}

extern "C" void kernel_launch(void* const* d_in, const int* in_sizes, int n_in,
                              void* d_out, int out_size, void* d_ws, size_t ws_size,
                              hipStream_t stream) {
    const float* x          = (const float*)d_in[0];
    const float* last_mu    = (const float*)d_in[1];
    const float* last_sigma = (const float*)d_in[2];
    const float* amu        = (const float*)d_in[3];
    const float* asig       = (const float*)d_in[4];
    const float* bmu        = (const float*)d_in[5];
    const float* bsig       = (const float*)d_in[6];
    const float* omu        = (const float*)d_in[7];
    const float* osig       = (const float*)d_in[8];
    const float* nu         = (const float*)d_in[9];
    const float* ns         = (const float*)d_in[10];
    const float* W1         = (const float*)d_in[11];
    const float* b1         = (const float*)d_in[12];
    const float* W2         = (const float*)d_in[13];
    const float* b2         = (const float*)d_in[14];
    const float* W3         = (const float*)d_in[15];
    const float* b3         = (const float*)d_in[16];
    float* out = (float*)d_out;

    uint4* wf = (uint4*)d_ws;   // 95,232 B fragment table (93 frags)
    prep_weights<<<93, 64, 0, stream>>>(W1, W2, W3, wf);

    hipFuncSetAttribute((const void*)ar_gas_v17,
                        hipFuncAttributeMaxDynamicSharedMemorySize, LDS_TOTAL);

    const int B = in_sizes[1];                 // 262144
    dim3 grid(B / BMROWS), block(THREADS);     // 2048 blocks x 512 threads
    ar_gas_v17<<<grid, block, LDS_TOTAL, stream>>>(
        x, last_mu, last_sigma,
        amu, asig, bmu, bsig, omu, osig, nu, ns,
        b1, b2, b3, wf, out);
}

// Round 18
// 83.295 us; speedup vs baseline: 1.7335x; 1.0003x over previous
//
#include <hip/hip_runtime.h>
#include <hip/hip_bf16.h>

typedef short v8s __attribute__((ext_vector_type(8)));
typedef float v4f __attribute__((ext_vector_type(4)));

#define THREADS 512      // 8 waves; each wave: 4 tiles x 16 rows = 64 rows
#define WAVES   8
#define NTILES  4
#define BMROWS  512      // rows per block
// d_ws frag order: W1 0-48, W2 49-76, W3 77-92 (slot s at LDS s*1024)
#define W1F     0
#define W2F     49
#define W3F     77
#define SLABB   95232                    // 93 frag slots end here
#define SLAB_STRIDE 264                  // bank += 2 per row -> low conflict
#define SLAB_SIZE   4224                 // 16 rows * 264
#define LDS_TOTAL   (SLABB + WAVES * SLAB_SIZE)   // 129,024 B -> 1 block/CU

__device__ __forceinline__ unsigned short f2bf(float f) {
    union { __hip_bfloat16 h; unsigned short u; } c;
    c.h = __float2bfloat16(f);
    return c.u;
}
__device__ __forceinline__ unsigned pk2(float a, float b) {
    return (unsigned)f2bf(a) | ((unsigned)f2bf(b) << 16);
}
__device__ __forceinline__ v4f mfma16(v8s a, v8s b, v4f c) {
    return __builtin_amdgcn_mfma_f32_16x16x32_bf16(a, b, c, 0, 0, 0);
}
__device__ __forceinline__ v8s mkfrag(float4 a, float4 b) {
    union { unsigned u[4]; v8s s; } t;
    t.u[0] = pk2(a.x, a.y); t.u[1] = pk2(a.z, a.w);
    t.u[2] = pk2(b.x, b.y); t.u[3] = pk2(b.z, b.w);
    return t.s;
}
__device__ __forceinline__ void gload_lds16(const void* g, void* l) {
    __builtin_amdgcn_global_load_lds(
        (const __attribute__((address_space(1))) void*)g,
        (__attribute__((address_space(3))) void*)l, 16, 0, 0);
}

// ---- prep: weights -> MFMA B-fragment layout (bf16, zero-padded) ----------
// frag(nt,kc): lane l holds B[k = kc*32+(l>>4)*8+j][n = nt*16+(l&15)], j=0..7
__global__ void prep_weights(const float* __restrict__ W1,
                             const float* __restrict__ W2,
                             const float* __restrict__ W3,
                             uint4* __restrict__ wf) {
    const int bid = blockIdx.x, l = threadIdx.x;
    const float* W; int K, N, KC, base, f;
    if (bid < 49)      { W = W1; K = 200; N = 100; KC = 7; base = W1F * 64; f = bid; }
    else if (bid < 77) { W = W2; K = 100; N = 100; KC = 4; base = W2F * 64; f = bid - 49; }
    else               { W = W3; K = 100; N = 64;  KC = 4; base = W3F * 64; f = bid - 77; }
    const int kc = f % KC;
    const int n  = (f / KC) * 16 + (l & 15);
    unsigned u[4];
    #pragma unroll
    for (int p = 0; p < 4; ++p) {
        const int k0 = kc * 32 + (l >> 4) * 8 + p * 2;
        const float a = (k0     < K && n < N) ? W[(size_t)k0 * N + n]       : 0.f;
        const float b = (k0 + 1 < K && n < N) ? W[(size_t)(k0 + 1) * N + n] : 0.f;
        u[p] = pk2(a, b);
    }
    wf[base + f * 64 + l] = make_uint4(u[0], u[1], u[2], u[3]);
}

__global__ __launch_bounds__(THREADS, 2)   // cap 256: the only no-spill regime
void ar_gas_v18(const float* __restrict__ x,
                const float* __restrict__ last_mu,
                const float* __restrict__ last_sigma,
                const float* __restrict__ p_amu, const float* __restrict__ p_as,
                const float* __restrict__ p_bmu, const float* __restrict__ p_bs,
                const float* __restrict__ p_omu, const float* __restrict__ p_os,
                const float* __restrict__ p_nu,  const float* __restrict__ p_ns,
                const float* __restrict__ b1, const float* __restrict__ b2,
                const float* __restrict__ b3,
                const uint4* __restrict__ wf,
                float* __restrict__ out)
{
    extern __shared__ __align__(16) unsigned char L[];
    const int tid  = threadIdx.x;
    const int lane = tid & 63;
    const int wid  = tid >> 6;
    const int l15  = lane & 15;
    const int l4   = lane >> 4;
    const int blk  = blockIdx.x;

    // GAS scalars (uniform)
    const float anu = *p_nu,  ans = *p_ns;
    const float aMu = *p_amu, aSg = *p_as;
    const float bMu = *p_bmu, bSg = *p_bs;
    const float oMu = *p_omu, oSg = *p_os;
    const float wS  = 1.f + __builtin_amdgcn_rcpf(anu);
    const float cmu = ans * aMu * wS;
    const float cs  = ans * aSg * wS;
    const float bs2 = bSg - ans * aSg;

#define XLOADT(dst, base_row, kk)                                       \
    { int kb = (kk) * 32 + l4 * 8;                                      \
      kb = (kb + 8 <= 200) ? kb : 168;   /* clamp x zero-pad W1 = 0 */  \
      const float* p_ = x + ((base_row) + l15) * 200;                   \
      dst[kk][0] = *(const float4*)(p_ + kb);                           \
      dst[kk][1] = *(const float4*)(p_ + kb + 4); }

    // wave rows: [gw0, gw0+64), tile t rows gw0 + t*16
    const size_t gw0 = (size_t)blk * BMROWS + (size_t)wid * 64;

    // ---- prologue burst: X(tile0) into 56 VGPRs + all 93 frags -> LDS ----
    float4 xv[7][2];
    #pragma unroll
    for (int kc = 0; kc < 7; ++kc) XLOADT(xv, gw0, kc);

    for (int s = wid; s < 93; s += WAVES)
        gload_lds16(wf + s * 64 + lane, L + s * 1024);
    __syncthreads();   // THE only barrier: X in regs, all frags resident

#define FRAG_W1(f)  (*(const uint4*)(&L[(W1F + (f)) * 1024 + lane * 16]))
#define FRAG_W2(f)  (*(const uint4*)(&L[(W2F + (f)) * 1024 + lane * 16]))
#define FRAG_W3(f)  (*(const uint4*)(&L[(W3F + (f)) * 1024 + lane * 16]))

    // affine slab bases (all ds offsets are compile-time constants)
    const int sb      = SLABB + wid * SLAB_SIZE;
    const int sb_epi  = sb + (l4 * 4) * SLAB_STRIDE + l15 * 2;  // +r*264+nt*32
    const int sb_rd   = sb + l15 * SLAB_STRIDE + l4 * 16;       // +kc*64
    const int sb_dpw  = sb + (l4 * 4) * SLAB_STRIDE + l15 * 4;  // +r*264+nt*64
    const int sb_gas  = sb + l15 * SLAB_STRIDE;                 // +q*16
    const int sb_st   = sb + l4 * SLAB_STRIDE + l15 * 16;       // +i*1056

    #pragma unroll 1
    for (int t = 0; t < NTILES; ++t) {
        const size_t gw = gw0 + t * 16;

        // state loads now; consumed at GAS ~6K cyc later
        const float mu_init = last_mu[gw + l15];
        const float s2_init = last_sigma[gw + l15];

        // ================= layer 1: h1 = relu(X @ W1 + b1) ==============
        v4f acc[7];
        #pragma unroll
        for (int nt = 0; nt < 7; ++nt) acc[nt] = (v4f){0.f, 0.f, 0.f, 0.f};
        #pragma unroll
        for (int kc = 0; kc < 7; ++kc) {
            uint4 bu[7];
            #pragma unroll
            for (int nt = 0; nt < 7; ++nt) bu[nt] = FRAG_W1(nt * 7 + kc);
            const v8s af = mkfrag(xv[kc][0], xv[kc][1]);   // regs only
            #pragma unroll
            for (int nt = 0; nt < 7; ++nt)
                acc[nt] = mfma16(af, *(const v8s*)&bu[nt], acc[nt]);
        }

        // xv is dead: issue NEXT tile's X loads now; they stream in under
        // epilogue + L2 + L3 + GAS + store (~15K cyc of zero-VMEM compute)
        if (t < NTILES - 1) {
            #pragma unroll
            for (int kc = 0; kc < 7; ++kc) XLOADT(xv, gw0 + (t + 1) * 16, kc);
        }

        // epilogue -> slab (bf16 [16 rows][stride 264]); transient bias
        {
            float bv[7];
            #pragma unroll
            for (int nt = 0; nt < 7; ++nt) {
                const int c = nt * 16 + l15;
                bv[nt] = (c < 100) ? b1[c] : 0.f;
            }
            #pragma unroll
            for (int nt = 0; nt < 7; ++nt)
                #pragma unroll
                for (int r = 0; r < 4; ++r) {
                    const float v = fmaxf(acc[nt][r] + bv[nt], 0.f);
                    *(unsigned short*)(&L[sb_epi + r * SLAB_STRIDE + nt * 32]) =
                        f2bf(v);
                }
        }
        // zero cols 112..127 (100..111 zero via zero-padded frags)
        if (lane < 32)
            *(uint4*)(&L[sb + (lane >> 1) * SLAB_STRIDE + 224 + (lane & 1) * 16]) =
                make_uint4(0, 0, 0, 0);

        // ================= layer 2: h2 = relu(h1 @ W2 + b2) =============
        v4f acc2[7];
        #pragma unroll
        for (int nt = 0; nt < 7; ++nt) acc2[nt] = (v4f){0.f, 0.f, 0.f, 0.f};
        #pragma unroll
        for (int kc = 0; kc < 4; ++kc) {
            uint4 bu[7];
            #pragma unroll
            for (int nt = 0; nt < 7; ++nt) bu[nt] = FRAG_W2(nt * 4 + kc);
            uint4 t0 = *(const uint4*)(&L[sb_rd + kc * 64]);
            const v8s af = *(v8s*)&t0;
            #pragma unroll
            for (int nt = 0; nt < 7; ++nt)
                acc2[nt] = mfma16(af, *(const v8s*)&bu[nt], acc2[nt]);
        }
        // h2 overwrites h1 in-place (in-wave DS ordering); pads keep zeros
        {
            float bv[7];
            #pragma unroll
            for (int nt = 0; nt < 7; ++nt) {
                const int c = nt * 16 + l15;
                bv[nt] = (c < 100) ? b2[c] : 0.f;
            }
            #pragma unroll
            for (int nt = 0; nt < 7; ++nt)
                #pragma unroll
                for (int r = 0; r < 4; ++r) {
                    const float v = fmaxf(acc2[nt][r] + bv[nt], 0.f);
                    *(unsigned short*)(&L[sb_epi + r * SLAB_STRIDE + nt * 32]) =
                        f2bf(v);
                }
        }

        // ================= layer 3: DP = h2 @ W3 + b3 ===================
        v4f acc3[4];
        #pragma unroll
        for (int nt = 0; nt < 4; ++nt) acc3[nt] = (v4f){0.f, 0.f, 0.f, 0.f};
        #pragma unroll
        for (int kc = 0; kc < 4; ++kc) {
            uint4 bu[4];
            #pragma unroll
            for (int nt = 0; nt < 4; ++nt) bu[nt] = FRAG_W3(nt * 4 + kc);
            uint4 t0 = *(const uint4*)(&L[sb_rd + kc * 64]);
            const v8s af = *(v8s*)&t0;
            #pragma unroll
            for (int nt = 0; nt < 4; ++nt)
                acc3[nt] = mfma16(af, *(const v8s*)&bu[nt], acc3[nt]);
        }
        // DP (f32 [16][64]) overwrites slab (h2 reads precede in program order)
        {
            float bv[4];
            #pragma unroll
            for (int nt = 0; nt < 4; ++nt) bv[nt] = b3[nt * 16 + l15];
            #pragma unroll
            for (int nt = 0; nt < 4; ++nt)
                #pragma unroll
                for (int r = 0; r < 4; ++r)
                    *(float*)(&L[sb_dpw + r * SLAB_STRIDE + nt * 64]) =
                        acc3[nt][r] + bv[nt];
        }

        // ====== Student-t GAS recurrence: lane<16 owns one row ======
        if (lane < 16) {
            float mu = mu_init;
            float s2 = s2_init;
#define GAS_STEP(Y, O)                                                  \
            {   const float e    = (Y) - mu;                            \
                const float nus2 = anu * s2;                            \
                const float den  = fmaf(e, e, nus2);                    \
                const float r0   = __builtin_amdgcn_rcpf(den);          \
                const float p    = e * nus2 * r0;                       \
                mu = fmaf(cmu, p, fmaf(bMu, mu, oMu));                  \
                s2 = fmaf(cs, e * p, fmaf(bs2, s2, oSg));               \
                (O) = fmaf((Y), __builtin_amdgcn_sqrtf(s2), mu); }
            #pragma unroll
            for (int q = 0; q < 16; ++q) {
                float4 d = *(float4*)(&L[sb_gas + q * 16]);
                float o0, o1, o2, o3;
                GAS_STEP(d.x, o0); GAS_STEP(d.y, o1);
                GAS_STEP(d.z, o2); GAS_STEP(d.w, o3);
                *(float4*)(&L[sb_gas + q * 16]) = make_float4(o0, o1, o2, o3);
            }
#undef GAS_STEP
        }

        // ============ wave-wide coalesced float4 store (no barrier) =======
        #pragma unroll
        for (int i = 0; i < 4; ++i) {
            float4 v = *(float4*)(&L[sb_st + i * (4 * SLAB_STRIDE)]);
            ((float4*)out)[gw * 16 + i * 64 + lane] = v;
        }
    }
#undef FRAG_W1
#undef FRAG_W2
#undef FRAG_W3
#undef XLOADT
}

extern "C" void kernel_launch(void* const* d_in, const int* in_sizes, int n_in,
                              void* d_out, int out_size, void* d_ws, size_t ws_size,
                              hipStream_t stream) {
    const float* x          = (const float*)d_in[0];
    const float* last_mu    = (const float*)d_in[1];
    const float* last_sigma = (const float*)d_in[2];
    const float* amu        = (const float*)d_in[3];
    const float* asig       = (const float*)d_in[4];
    const float* bmu        = (const float*)d_in[5];
    const float* bsig       = (const float*)d_in[6];
    const float* omu        = (const float*)d_in[7];
    const float* osig       = (const float*)d_in[8];
    const float* nu         = (const float*)d_in[9];
    const float* ns         = (const float*)d_in[10];
    const float* W1         = (const float*)d_in[11];
    const float* b1         = (const float*)d_in[12];
    const float* W2         = (const float*)d_in[13];
    const float* b2         = (const float*)d_in[14];
    const float* W3         = (const float*)d_in[15];
    const float* b3         = (const float*)d_in[16];
    float* out = (float*)d_out;

    uint4* wf = (uint4*)d_ws;   // 95,232 B fragment table (93 frags)
    prep_weights<<<93, 64, 0, stream>>>(W1, W2, W3, wf);

    hipFuncSetAttribute((const void*)ar_gas_v18,
                        hipFuncAttributeMaxDynamicSharedMemorySize, LDS_TOTAL);

    const int B = in_sizes[1];                 // 262144
    dim3 grid(B / BMROWS), block(THREADS);     // 512 blocks x 512 threads
    ar_gas_v18<<<grid, block, LDS_TOTAL, stream>>>(
        x, last_mu, last_sigma,
        amu, asig, bmu, bsig, omu, osig, nu, ns,
        b1, b2, b3, wf, out);
}